// Round 7
// baseline (338.564 us; speedup 1.0000x reference)
//
#include <hip/hip_runtime.h>
#include <hip/hip_bf16.h>
#include <type_traits>

typedef __attribute__((ext_vector_type(8))) short short8;
typedef __attribute__((ext_vector_type(4))) short s16x4;
typedef __attribute__((ext_vector_type(4))) float f32x4;
typedef unsigned short u16;
typedef unsigned int   u32;
typedef unsigned long long u64;

// B=4, S=2048, D=1024, H=16, DK=64, M = B*S = 8192

// MFMA16 only resolved for the DEVICE pass; host pass gets an inert stub
// (host never executes device bodies, but it does semantic-check them).
#if defined(__HIP_DEVICE_COMPILE__)
  #if __has_builtin(__builtin_amdgcn_mfma_f32_16x16x16bf16_1k)
    #define MFMA16(a, b, c) __builtin_amdgcn_mfma_f32_16x16x16bf16_1k(a, b, c, 0, 0, 0)
  #else
    #define MFMA16(a, b, c) __builtin_amdgcn_mfma_f32_16x16x16_bf16(a, b, c, 0, 0, 0)
  #endif
#else
  #define MFMA16(a, b, c) (c)
#endif

#define EXP2F(x) exp2f(x)  // lowers to v_exp_f32 on gfx950

static __device__ __forceinline__ u16 f2b(float f) {
  u32 u = __builtin_bit_cast(u32, f);
  u = (u + 0x7fffu + ((u >> 16) & 1u)) >> 16;
  return (u16)u;
}
static __device__ __forceinline__ float b2f(u16 h) {
  return __builtin_bit_cast(float, ((u32)h) << 16);
}
static __device__ __forceinline__ u32 pkbf(float a, float b) {
  union { __hip_bfloat162 t; u32 u; } c;
  c.t = __float22bfloat162_rn(make_float2(a, b));
  return c.u;
}

typedef __attribute__((address_space(1))) const unsigned int gas_u32;
typedef __attribute__((address_space(3))) unsigned int las_u32;
static __device__ __forceinline__ void glds16(const u16* g, u16* l) {
  __builtin_amdgcn_global_load_lds((gas_u32*)g, (las_u32*)l, 16, 0, 0);
}

// ---------------- fused fp32 -> bf16 convert (x + 4 weights) ----------------
__global__ __launch_bounds__(256) void cvt_all(
    const float* __restrict__ x, const float* __restrict__ wq,
    const float* __restrict__ wk, const float* __restrict__ wv,
    const float* __restrict__ wo, u16* __restrict__ xb, u16* __restrict__ wqb,
    u16* __restrict__ wkb, u16* __restrict__ wvb, u16* __restrict__ wob) {
  int u = blockIdx.x * 256 + threadIdx.x;  // unit of 4 floats
  if (u >= 3145728) return;
  const float* src; u16* dst; int off;
  if (u < 2097152) { src = x; dst = xb; off = u; }
  else {
    int t = u - 2097152;
    int w = t >> 18;
    off = t & 0x3FFFF;
    src = (w == 0) ? wq : (w == 1) ? wk : (w == 2) ? wv : wo;
    dst = (w == 0) ? wqb : (w == 1) ? wkb : (w == 2) ? wvb : wob;
  }
  int i = off * 4;
  float4 v = *(const float4*)(src + i);
  union { u16 us[4]; u64 ull; } o;
  o.us[0] = f2b(v.x); o.us[1] = f2b(v.y); o.us[2] = f2b(v.z); o.us[3] = f2b(v.w);
  *(u64*)(dst + i) = o.ull;
}

// ---------------- GEMM: C[m,n] = sum_k A[m,k]*B[n,k]  (B^T form) ----------
template <typename OT>
static __device__ __forceinline__ void gemm_body(const u16* __restrict__ A,
                                                 const u16* __restrict__ B,
                                                 OT* __restrict__ C,
                                                 int m0, int n0) {
  __shared__ u16 As[4096];
  __shared__ u16 Bs[4096];

  const int tid  = threadIdx.x;
  const int lane = tid & 63;
  const int wv   = tid >> 6;
  const int quad = lane >> 4;
  const int cc   = lane & 15;
  const int wr   = wv >> 1;
  const int wc   = wv & 1;

  f32x4 acc[4][4];
#pragma unroll
  for (int i = 0; i < 4; i++)
#pragma unroll
    for (int j = 0; j < 4; j++) acc[i][j] = (f32x4){0.f, 0.f, 0.f, 0.f};

  const int p0 = wv * 128 + lane;
  const int p1 = p0 + 64;
  const int r0 = p0 >> 2, g0 = (p0 & 3) ^ (r0 & 3);
  const int r1 = p1 >> 2, g1 = (p1 & 3) ^ (r1 & 3);
  const u16* gA0 = A + (size_t)(m0 + r0) * 1024 + g0 * 8;
  const u16* gA1 = A + (size_t)(m0 + r1) * 1024 + g1 * 8;
  const u16* gB0 = B + (size_t)(n0 + r0) * 1024 + g0 * 8;
  const u16* gB1 = B + (size_t)(n0 + r1) * 1024 + g1 * 8;
  u16* lA = As + wv * 1024;
  u16* lB = Bs + wv * 1024;

  for (int k0 = 0; k0 < 1024; k0 += 32) {
    __syncthreads();
    glds16(gA0 + k0, lA);
    glds16(gA1 + k0, lA + 512);
    glds16(gB0 + k0, lB);
    glds16(gB1 + k0, lB + 512);
    __syncthreads();

    short8 af[4], bf[4];
#pragma unroll
    for (int mt = 0; mt < 4; mt++) {
      int ra = wr * 64 + mt * 16 + cc;
      af[mt] = *(const short8*)&As[ra * 32 + ((quad ^ (ra & 3)) * 8)];
    }
#pragma unroll
    for (int nt = 0; nt < 4; nt++) {
      int rb = wc * 64 + nt * 16 + cc;
      bf[nt] = *(const short8*)&Bs[rb * 32 + ((quad ^ (rb & 3)) * 8)];
    }
#pragma unroll
    for (int mt = 0; mt < 4; mt++)
#pragma unroll
      for (int nt = 0; nt < 4; nt++)
        acc[mt][nt] = __builtin_amdgcn_mfma_f32_16x16x32_bf16(af[mt], bf[nt], acc[mt][nt], 0, 0, 0);
  }

#pragma unroll
  for (int mt = 0; mt < 4; mt++)
#pragma unroll
    for (int nt = 0; nt < 4; nt++)
#pragma unroll
      for (int r = 0; r < 4; r++) {
        int row = m0 + wr * 64 + mt * 16 + quad * 4 + r;
        int col = n0 + wc * 64 + nt * 16 + cc;
        if constexpr (std::is_same_v<OT, float>)
          C[(size_t)row * 1024 + col] = acc[mt][nt][r];
        else
          C[(size_t)row * 1024 + col] = f2b(acc[mt][nt][r]);
      }
}

__global__ __launch_bounds__(256) void gemm_qkv(const u16* __restrict__ A,
                                                const u16* __restrict__ Bq,
                                                const u16* __restrict__ Bk,
                                                const u16* __restrict__ Bv,
                                                u16* __restrict__ Q,
                                                u16* __restrict__ K,
                                                u16* __restrict__ V) {
  int sel = blockIdx.x >> 3;
  const u16* B = (sel == 0) ? Bq : (sel == 1) ? Bk : Bv;
  u16* C = (sel == 0) ? Q : (sel == 1) ? K : V;
  gemm_body<u16>(A, B, C, blockIdx.y * 128, (blockIdx.x & 7) * 128);
}

__global__ __launch_bounds__(256) void gemm_out(const u16* __restrict__ A,
                                                const u16* __restrict__ B,
                                                float* __restrict__ C) {
  gemm_body<float>(A, B, C, blockIdx.y * 128, blockIdx.x * 128);
}

// ---------------- RoPE on Q and K (in place, bf16) ----------------
// Q pre-scaled by (1/sqrt(64)) * log2(e) so attention softmax runs in
// exp2 domain with no per-score multiply.
__global__ __launch_bounds__(256) void rope_kernel(u16* __restrict__ Q,
                                                   u16* __restrict__ K,
                                                   const int* __restrict__ pos) {
  u16* T = blockIdx.y ? K : Q;
  const float sc = blockIdx.y ? 1.0f : 0.18033688011112042f;  // 0.125*log2(e)
  int idx = blockIdx.x * 256 + threadIdx.x;
  int row = idx >> 9;
  int p   = idx & 511;
  int i   = p & 31;
  int col = (p >> 5) * 64 + 2 * i;
  int s   = row & 2047;
  float ps  = (float)pos[s];
  float inv = exp2f(-(float)i * 0.41524101186092033f);
  float ang = ps * inv;
  float sn, cs;
  sincosf(ang, &sn, &cs);
  u32 v = *(u32*)(T + (size_t)row * 1024 + col);
  float x1 = b2f((u16)(v & 0xffffu));
  float x2 = b2f((u16)(v >> 16));
  float y1 = (x1 * cs - x2 * sn) * sc;
  float y2 = (x1 * sn + x2 * cs) * sc;
  *(u32*)(T + (size_t)row * 1024 + col) = (u32)f2b(y1) | ((u32)f2b(y2) << 16);
}

// ---------------- transpose V: (b,s,h,d) -> Vt[(b,h,d), k'] ----------------
// Column permutation within each 32-key group so attention can read two
// K=16 PV fragments with ONE ds_read_b128:
//   stored position p (0..31) holds k = ((p>>2)&1)*16 + (p>>3)*4 + (p&3)
__global__ __launch_bounds__(256) void transpose_v(const u16* __restrict__ V,
                                                   u16* __restrict__ Vt) {
  __shared__ u16 t[64][65];
  int s0 = blockIdx.x * 64;
  int bh = blockIdx.y;
  int b = bh >> 4, h = bh & 15;
  int tid = threadIdx.x;
  int r = tid >> 2, ch = (tid & 3) * 16;
  const u16* src = V + (size_t)(b * 2048 + s0 + r) * 1024 + h * 64 + ch;
  union { uint4 v[2]; u16 us[16]; } tmp;
  tmp.v[0] = *(const uint4*)src;
  tmp.v[1] = *(const uint4*)(src + 8);
#pragma unroll
  for (int j = 0; j < 16; j++) t[r][ch + j] = tmp.us[j];
  __syncthreads();
  union { uint4 v[2]; u16 us[16]; } o;
#pragma unroll
  for (int j = 0; j < 16; j++) {
    int p  = ch + j;  // destination column within the 64-key tile
    int kg = (p & ~31) + ((p >> 2) & 1) * 16 + (((p & 31) >> 3) * 4) + (p & 3);
    o.us[j] = t[kg][r];
  }
  u16* dst = Vt + (size_t)(bh * 64 + r) * 2048 + s0 + ch;
  *(uint4*)dst = o.v[0];
  *(uint4*)(dst + 8) = o.v[1];
}

// ---------------- causal flash attention V5 ----------------
// Pair-balanced: block (bh, y) processes q-tiles qtA=15-y then qtB=y --
// exactly 17 k-tile iterations for every block (perfect static balance).
// Double-buffered K/V LDS staged via global_load_lds(16B); one barrier/iter;
// prefetch of tile t+1 overlaps compute on t. K/V fragment LDS reads hoisted
// across mt (shared) and V read as b128 (two K=16 fragments per read).
// S^T = K·Q^T; P stays in registers (C-layout == A-layout of 16x16x16 MFMA).
__global__ __launch_bounds__(256) void attn_kernel(const u16* __restrict__ Q,
                                                   const u16* __restrict__ K,
                                                   const u16* __restrict__ Vt,
                                                   u16* __restrict__ O) {
  __shared__ u16 Ks[2][8192];  // [buf][128 keys x 64 d], 8-chunk XOR swizzle
  __shared__ u16 Vs[2][8192];  // [buf][64 d x 128 k'], 16-chunk rotate swizzle

  const int bh = blockIdx.x;
  const int y  = blockIdx.y;          // 0..7
  const int qtA = 15 - y, qtB = y;
  const int nA = qtA + 1;             // iters in job A; total always 17
  const int b = bh >> 4, h = bh & 15;
  const int tid  = threadIdx.x;
  const int lane = tid & 63;
  const int wv   = tid >> 6;
  const int quad = lane >> 4;
  const int cc   = lane & 15;

  // Q fragments for both jobs (B-operand of 16x16x32: B[n=cc][k=quad*8+j])
  short8 qcur[2][2], qfB[2][2];
#pragma unroll
  for (int mt = 0; mt < 2; mt++) {
    const u16* qa = Q + (size_t)(b * 2048 + qtA * 128 + wv * 32 + mt * 16 + cc) * 1024 + h * 64;
    qcur[mt][0] = *(const short8*)(qa + quad * 8);
    qcur[mt][1] = *(const short8*)(qa + 32 + quad * 8);
    const u16* qb = Q + (size_t)(b * 2048 + qtB * 128 + wv * 32 + mt * 16 + cc) * 1024 + h * 64;
    qfB[mt][0] = *(const short8*)(qb + quad * 8);
    qfB[mt][1] = *(const short8*)(qb + 32 + quad * 8);
  }

  f32x4 o_acc[2][4];
  float m_i[2] = {-3.0e38f, -3.0e38f}, l_i[2] = {0.f, 0.f};
#pragma unroll
  for (int mt = 0; mt < 2; mt++)
#pragma unroll
    for (int nt = 0; nt < 4; nt++) o_acc[mt][nt] = (f32x4){0.f, 0.f, 0.f, 0.f};

  // ---- staging addresses ----
  // K: wave wv rows wv*32 + j*8 + (lane>>3); chunk pos=lane&7 holds g=pos^(row&7)
  const u16* Kp = K + ((size_t)(b * 2048) + wv * 32 + (lane >> 3)) * 1024 + h * 64 +
                  (((lane & 7) ^ (lane >> 3)) * 8);
  // V: wave wv rows wv*16 + j*4 + (lane>>4); phys pos=lane&15 holds cl=(pos-row)&15
  const u16* Vp[4];
#pragma unroll
  for (int j = 0; j < 4; j++) {
    int rl = wv * 16 + j * 4 + (lane >> 4);
    int cl = ((lane & 15) - rl) & 15;
    Vp[j] = Vt + ((size_t)(bh * 64) + rl) * 2048 + cl * 8;
  }

  auto stage = [&](int kt, int pp) {
    u16* kb = &Ks[pp][wv * 2048];
    u16* vb = &Vs[pp][wv * 2048];
#pragma unroll
    for (int j = 0; j < 4; j++) {
      glds16(Kp + (size_t)kt * 131072 + j * 8192, kb + j * 512);
      glds16(Vp[j] + kt * 128, vb + j * 512);
    }
  };

  auto store_O = [&](int q0) {
#pragma unroll
    for (int mt = 0; mt < 2; ++mt) {
      float l = l_i[mt];
      l += __shfl_xor(l, 16);
      l += __shfl_xor(l, 32);
      const float linv = 1.0f / l;
      f32x4 li4;
#pragma unroll
      for (int r = 0; r < 4; ++r) li4[r] = __shfl(linv, quad * 4 + r);
      const int rowb = b * 2048 + q0 + wv * 32 + mt * 16 + quad * 4;
#pragma unroll
      for (int nt = 0; nt < 4; ++nt)
#pragma unroll
        for (int r = 0; r < 4; ++r)
          O[(size_t)(rowb + r) * 1024 + h * 64 + nt * 16 + cc] =
              f2b(o_acc[mt][nt][r] * li4[r]);
    }
  };

  const int pk0 = (quad ^ (cc & 7)) * 8;  // Ks chunk offset for g=quad

  stage(0, 0);
  int p = 0;

  for (int it = 0; it < 17; ++it) {
    const bool inA = it < nA;
    const int kt = inA ? it : it - nA;
    const int qt = inA ? qtA : qtB;

    __syncthreads();  // drains prefetch glds (vmcnt) + guards buffer reuse

    if (it + 1 < 17) {  // prefetch next tile into other buffer
      int kt2 = (it + 1 < nA) ? it + 1 : it + 1 - nA;
      stage(kt2, p ^ 1);
    }

    // ---- S^T = K Q^T : rows=keys(quad*4+r), cols=q(cc); both mt share bk ----
    f32x4 s[2][8];
#pragma unroll
    for (int nt = 0; nt < 8; ++nt) {
      const int rbase = (nt * 16 + cc) * 64;
      short8 bk0 = *(const short8*)&Ks[p][rbase + pk0];
      short8 bk1 = *(const short8*)&Ks[p][rbase + (pk0 ^ 32)];
#pragma unroll
      for (int mt = 0; mt < 2; ++mt) {
        f32x4 z = (f32x4){0.f, 0.f, 0.f, 0.f};
        z = __builtin_amdgcn_mfma_f32_16x16x32_bf16(bk0, qcur[mt][0], z, 0, 0, 0);
        s[mt][nt] = __builtin_amdgcn_mfma_f32_16x16x32_bf16(bk1, qcur[mt][1], z, 0, 0, 0);
      }
    }

    if (kt == qt) {  // diagonal tile: causal mask (wave-uniform branch)
#pragma unroll
      for (int mt = 0; mt < 2; ++mt) {
        const int qloc = wv * 32 + mt * 16 + cc;
        const int kb = quad * 4;
#pragma unroll
        for (int nt = 0; nt < 8; ++nt)
#pragma unroll
          for (int r = 0; r < 4; ++r)
            if (kb + nt * 16 + r > qloc) s[mt][nt][r] = -3.0e38f;
      }
    }

    // ---- online softmax (exp2 domain; scale pre-folded into Q) ----
    s16x4 pf[2][8];
    float al[2];
#pragma unroll
    for (int mt = 0; mt < 2; ++mt) {
      float mx = s[mt][0][0];
#pragma unroll
      for (int nt = 0; nt < 8; ++nt)
#pragma unroll
        for (int r = 0; r < 4; ++r) mx = fmaxf(mx, s[mt][nt][r]);
      mx = fmaxf(mx, __shfl_xor(mx, 16));
      mx = fmaxf(mx, __shfl_xor(mx, 32));
      const float mn = fmaxf(m_i[mt], mx);
      al[mt] = EXP2F(m_i[mt] - mn);
      m_i[mt] = mn;

      float ps = 0.f;
#pragma unroll
      for (int nt = 0; nt < 8; ++nt) {
        float e0 = EXP2F(s[mt][nt][0] - mn);
        float e1 = EXP2F(s[mt][nt][1] - mn);
        float e2 = EXP2F(s[mt][nt][2] - mn);
        float e3 = EXP2F(s[mt][nt][3] - mn);
        ps += (e0 + e1) + (e2 + e3);
        union { u32 w[2]; s16x4 v; } pu;
        pu.w[0] = pkbf(e0, e1);
        pu.w[1] = pkbf(e2, e3);
        pf[mt][nt] = pu.v;
      }
      l_i[mt] = l_i[mt] * al[mt] + ps;

      f32x4 al4;
#pragma unroll
      for (int r = 0; r < 4; ++r) al4[r] = __shfl(al[mt], quad * 4 + r);
#pragma unroll
      for (int nt = 0; nt < 4; ++nt) o_acc[mt][nt] *= al4;
    }

    // ---- PV: one b128 V read feeds 2 fragments x 2 mt (4 MFMAs) ----
#pragma unroll
    for (int nt = 0; nt < 4; ++nt) {
      const int rv = (nt * 16 + cc) * 128;
#pragma unroll
      for (int g = 0; g < 4; ++g) {
        short8 bv = *(const short8*)&Vs[p][rv + (((g * 4 + quad) + cc) & 15) * 8];
        s16x4 lo = __builtin_shufflevector(bv, bv, 0, 1, 2, 3);
        s16x4 hi = __builtin_shufflevector(bv, bv, 4, 5, 6, 7);
#pragma unroll
        for (int mt = 0; mt < 2; ++mt) {
          o_acc[mt][nt] = MFMA16(pf[mt][2 * g], lo, o_acc[mt][nt]);
          o_acc[mt][nt] = MFMA16(pf[mt][2 * g + 1], hi, o_acc[mt][nt]);
        }
      }
    }

    if (it == nA - 1) {  // job A done: store, reset state, switch Q frags
      store_O(qtA * 128);
      m_i[0] = m_i[1] = -3.0e38f;
      l_i[0] = l_i[1] = 0.f;
#pragma unroll
      for (int mt = 0; mt < 2; mt++) {
#pragma unroll
        for (int nt = 0; nt < 4; nt++) o_acc[mt][nt] = (f32x4){0.f, 0.f, 0.f, 0.f};
        qcur[mt][0] = qfB[mt][0];
        qcur[mt][1] = qfB[mt][1];
      }
    }
    p ^= 1;
  }

  store_O(qtB * 128);
}

// ---------------- launch ----------------
extern "C" void kernel_launch(void* const* d_in, const int* in_sizes, int n_in,
                              void* d_out, int out_size, void* d_ws, size_t ws_size,
                              hipStream_t stream) {
  const float* x  = (const float*)d_in[0];
  const float* wq = (const float*)d_in[1];
  const float* wk = (const float*)d_in[2];
  const float* wv = (const float*)d_in[3];
  const float* wo = (const float*)d_in[4];
  const int* pos  = (const int*)d_in[5];
  float* out = (float*)d_out;

  char* ws = (char*)d_ws;
  // [0,16M): xb -> later Vt   [16M,24M): weights bf16
  // [24M,40M): Q  [40M,56M): K  [56M,72M): V -> later attn_out
  u16* xb  = (u16*)(ws);
  u16* vt  = (u16*)(ws);
  u16* wqb = (u16*)(ws + (16ull << 20));
  u16* wkb = (u16*)(ws + (18ull << 20));
  u16* wvb = (u16*)(ws + (20ull << 20));
  u16* wob = (u16*)(ws + (22ull << 20));
  u16* Qb  = (u16*)(ws + (24ull << 20));
  u16* Kb  = (u16*)(ws + (40ull << 20));
  u16* Vb  = (u16*)(ws + (56ull << 20));
  u16* aO  = Vb;

  cvt_all<<<12288, 256, 0, stream>>>(x, wq, wk, wv, wo, xb, wqb, wkb, wvb, wob);
  gemm_qkv<<<dim3(24, 64), 256, 0, stream>>>(xb, wqb, wkb, wvb, Qb, Kb, Vb);
  rope_kernel<<<dim3(16384, 2), 256, 0, stream>>>(Qb, Kb, pos);
  transpose_v<<<dim3(32, 64), 256, 0, stream>>>(Vb, vt);
  attn_kernel<<<dim3(64, 8), 256, 0, stream>>>(Qb, Kb, vt, aO);
  gemm_out<<<dim3(8, 64), 256, 0, stream>>>(aO, wob, out);
}